// Round 3
// baseline (716.658 us; speedup 1.0000x reference)
//
#include <hip/hip_runtime.h>

#define KN 100000
#define KEG 600000
#define KE 600000

using u16 = unsigned short;
typedef __bf16 bf16x8 __attribute__((ext_vector_type(8)));
typedef float f32x4 __attribute__((ext_vector_type(4)));

__device__ __forceinline__ float b2f(u16 u) { return __uint_as_float(((unsigned)u) << 16); }
__device__ __forceinline__ u16 f2b(float f) {
  unsigned u = __float_as_uint(f);
  u += 0x7FFF + ((u >> 16) & 1);  // round-to-nearest-even
  return (u16)(u >> 16);
}
__device__ __forceinline__ int imin(int a, int b) { return a < b ? a : b; }

// zero agg [N*64] and denom [N]
__global__ __launch_bounds__(256) void k_init(float* agg, float* denom) {
  int idx = blockIdx.x * 256 + threadIdx.x;
  if (idx < KN * 64) agg[idx] = 0.f;
  if (idx < KN) denom[idx] = 0.f;
}

// layer0 transform: h = pos @ W0 (in=3), a_s = <h,att_src>, a_d = <h,att_dst>
__global__ __launch_bounds__(256) void k_transform0(
    const float* __restrict__ pos, const float* __restrict__ W0,
    const float* __restrict__ att_s, const float* __restrict__ att_d,
    u16* __restrict__ h, float* __restrict__ a_s, float* __restrict__ a_d) {
  int lane = threadIdx.x & 63;
  int n = blockIdx.x * 4 + (threadIdx.x >> 6);
  if (n >= KN) return;
  float p0 = pos[n * 3 + 0], p1 = pos[n * 3 + 1], p2 = pos[n * 3 + 2];
  float hv = p0 * W0[lane] + p1 * W0[64 + lane] + p2 * W0[128 + lane];
  h[n * 64 + lane] = f2b(hv);
  float s = hv * att_s[lane];
  float d = hv * att_d[lane];
  for (int off = 1; off < 64; off <<= 1) { s += __shfl_xor(s, off); d += __shfl_xor(d, off); }
  if (lane == 0) { a_s[n] = s; a_d[n] = d; }
}

// layer1 transform: h = x1 @ W1 (64x64 via wave shuffle broadcast)
__global__ __launch_bounds__(256) void k_transform1(
    const u16* __restrict__ x, const float* __restrict__ W1,
    const float* __restrict__ att_s, const float* __restrict__ att_d,
    u16* __restrict__ h, float* __restrict__ a_s, float* __restrict__ a_d) {
  int lane = threadIdx.x & 63;
  int n = blockIdx.x * 4 + (threadIdx.x >> 6);
  if (n >= KN) return;
  float xv = b2f(x[n * 64 + lane]);
  float hv = 0.f;
#pragma unroll 16
  for (int k = 0; k < 64; ++k) hv += __shfl(xv, k) * W1[k * 64 + lane];
  h[n * 64 + lane] = f2b(hv);
  float s = hv * att_s[lane];
  float d = hv * att_d[lane];
  for (int off = 1; off < 64; off <<= 1) { s += __shfl_xor(s, off); d += __shfl_xor(d, off); }
  if (lane == 0) { a_s[n] = s; a_d[n] = d; }
}

// per global edge: e = exp(leaky_relu(a_s[src]+a_d[dst])); denom[dst] += e
// (max-subtraction skipped: alphas O(1..10); weights e/denom are mathematically
//  identical to the max-shifted form, exp safe in f32)
__global__ __launch_bounds__(256) void k_edge_denom(
    const int* __restrict__ gsrc, const int* __restrict__ gdst,
    const float* __restrict__ a_s, const float* __restrict__ a_d,
    float* __restrict__ e_arr, float* __restrict__ denom) {
  int e = blockIdx.x * 256 + threadIdx.x;
  if (e >= KEG) return;
  int s = gsrc[e], d = gdst[e];
  float al = a_s[s] + a_d[d];
  al = al > 0.f ? al : 0.2f * al;
  float ex = __expf(al);
  e_arr[e] = ex;
  atomicAdd(denom + d, ex);
}

// per global edge: agg[dst] += h[src] * (e/denom[dst]); one wave per edge, lane=channel
__global__ __launch_bounds__(256) void k_scatter(
    const int* __restrict__ gsrc, const int* __restrict__ gdst,
    const u16* __restrict__ h, const float* __restrict__ e_arr,
    const float* __restrict__ denom, float* __restrict__ agg) {
  int lane = threadIdx.x & 63;
  int e = blockIdx.x * 4 + (threadIdx.x >> 6);
  if (e >= KEG) return;
  int s = gsrc[e], d = gdst[e];
  float w = e_arr[e] / (denom[d] + 1e-16f);
  atomicAdd(agg + d * 64 + lane, b2f(h[s * 64 + lane]) * w);
}

// x = elu(agg + bias) -> bf16
__global__ __launch_bounds__(256) void k_finalize(
    const float* __restrict__ agg, const float* __restrict__ bias, u16* __restrict__ xbf) {
  int idx = blockIdx.x * 256 + threadIdx.x;
  if (idx >= KN * 64) return;
  float v = agg[idx] + bias[idx & 63];
  v = v > 0.f ? v : expm1f(v);
  xbf[idx] = f2b(v);
}

// Pre-swizzle Wm1 rows 0..127 into MFMA B-fragment order (bf16):
// frag (nt,kt): lane holds B[k=kt*32+(lane>>4)*8+j][n=nt*16+(lane&15)], j=0..7.
__global__ __launch_bounds__(256) void k_wm1t(const float* __restrict__ wm1, u16* __restrict__ wm1t) {
  int idx = blockIdx.x * 256 + threadIdx.x;  // < 33*4*64*8 = 67584
  if (idx >= 33 * 4 * 64 * 8) return;
  int j = idx & 7;
  int lane = (idx >> 3) & 63;
  int kt = (idx >> 9) & 3;
  int nt = idx >> 11;
  int n = nt * 16 + (lane & 15);
  int k = kt * 32 + (lane >> 4) * 8 + j;
  wm1t[idx] = (n < 520) ? f2b(wm1[k * 520 + n]) : (u16)0;
}

// Fused edge MLP: gather ef=[x[src],x[dst],ea], GEMM vs Wm1 (K=128 MFMA + rank-2
// VALU for rows 128/129), +bm1, ELU, dot Wm2, +bm2. Wave = 64 edges. f32 output.
__global__ __launch_bounds__(256) void k_edge_mlp(
    const int* __restrict__ eidx, const u16* __restrict__ x2bf,
    const float* __restrict__ eattr, const u16* __restrict__ wm1t,
    const float* __restrict__ wm1, const float* __restrict__ bm1,
    const float* __restrict__ wm2, const float* __restrict__ bm2,
    float* __restrict__ out) {
  int lane = threadIdx.x & 63;
  int wave = threadIdx.x >> 6;
  int base = blockIdx.x * 256 + wave * 64;
  int m = lane & 15, q = lane >> 4;

  // A fragments: A[m=lane&15][k=q*8+j]; whole 16x160 ef tile lives in regs
  bf16x8 A[4][4];
#pragma unroll
  for (int s = 0; s < 4; ++s) {
    int row = imin(base + s * 16 + m, KE - 1);
    int es = eidx[row], ed = eidx[KE + row];
    const bf16x8* ps = (const bf16x8*)(x2bf + es * 64);
    const bf16x8* pd = (const bf16x8*)(x2bf + ed * 64);
    A[s][0] = ps[q];      // k 0..31   (x_src lo)
    A[s][1] = ps[q + 4];  // k 32..63  (x_src hi)
    A[s][2] = pd[q];      // k 64..95  (x_dst lo)
    A[s][3] = pd[q + 4];  // k 96..127 (x_dst hi)
  }

  // edge_attr per C-row (row = q*4+r within subtile)
  float ea0[4][4], ea1[4][4];
#pragma unroll
  for (int s = 0; s < 4; ++s)
#pragma unroll
    for (int r = 0; r < 4; ++r) {
      int row = imin(base + s * 16 + q * 4 + r, KE - 1);
      ea0[s][r] = eattr[row * 2 + 0];
      ea1[s][r] = eattr[row * 2 + 1];
    }

  float osum[4][4];
#pragma unroll
  for (int s = 0; s < 4; ++s)
#pragma unroll
    for (int r = 0; r < 4; ++r) osum[s][r] = 0.f;

  const bf16x8* bt = (const bf16x8*)wm1t;
#pragma unroll 1
  for (int nt = 0; nt < 33; ++nt) {
    int nn = nt * 16 + m;               // hidden-unit column for this lane
    int nc = imin(nn, 519);
    float valid = (nn < 520) ? 1.f : 0.f;
    float bias = bm1[nc];
    float w2 = wm2[nc] * valid;         // zero-out padded columns
    float w128 = wm1[128 * 520 + nc];
    float w129 = wm1[129 * 520 + nc];
    bf16x8 B0 = bt[(nt * 4 + 0) * 64 + lane];
    bf16x8 B1 = bt[(nt * 4 + 1) * 64 + lane];
    bf16x8 B2 = bt[(nt * 4 + 2) * 64 + lane];
    bf16x8 B3 = bt[(nt * 4 + 3) * 64 + lane];
#pragma unroll
    for (int s = 0; s < 4; ++s) {
      f32x4 acc = {0.f, 0.f, 0.f, 0.f};
      acc = __builtin_amdgcn_mfma_f32_16x16x32_bf16(A[s][0], B0, acc, 0, 0, 0);
      acc = __builtin_amdgcn_mfma_f32_16x16x32_bf16(A[s][1], B1, acc, 0, 0, 0);
      acc = __builtin_amdgcn_mfma_f32_16x16x32_bf16(A[s][2], B2, acc, 0, 0, 0);
      acc = __builtin_amdgcn_mfma_f32_16x16x32_bf16(A[s][3], B3, acc, 0, 0, 0);
#pragma unroll
      for (int r = 0; r < 4; ++r) {  // C/D: col=lane&15, row=q*4+r
        float hv = acc[r] + bias + ea0[s][r] * w128 + ea1[s][r] * w129;
        hv = hv > 0.f ? hv : (__expf(hv) - 1.f);  // ELU
        osum[s][r] += hv * w2;
      }
    }
  }

  float b2v = bm2[0];
#pragma unroll
  for (int s = 0; s < 4; ++s)
#pragma unroll
    for (int r = 0; r < 4; ++r) {
      float v = osum[s][r];
      v += __shfl_xor(v, 1);
      v += __shfl_xor(v, 2);
      v += __shfl_xor(v, 4);
      v += __shfl_xor(v, 8);  // sum the 16 column-lanes of this row
      if (m == 0) {
        int row = base + s * 16 + q * 4 + r;
        if (row < KE) out[row] = v + b2v;
      }
    }
}

extern "C" void kernel_launch(void* const* d_in, const int* in_sizes, int n_in,
                              void* d_out, int out_size, void* d_ws, size_t ws_size,
                              hipStream_t stream) {
  const float* pos  = (const float*)d_in[0];
  const int* eidx   = (const int*)d_in[1];
  const int* geidx  = (const int*)d_in[2];
  const float* eattr= (const float*)d_in[3];
  const float* W0   = (const float*)d_in[4];
  const float* as0  = (const float*)d_in[5];
  const float* ad0  = (const float*)d_in[6];
  const float* b0   = (const float*)d_in[7];
  const float* W1   = (const float*)d_in[8];
  const float* as1  = (const float*)d_in[9];
  const float* ad1  = (const float*)d_in[10];
  const float* b1   = (const float*)d_in[11];
  const float* Wm1  = (const float*)d_in[12];
  const float* bm1  = (const float*)d_in[13];
  const float* Wm2  = (const float*)d_in[14];
  const float* bm2  = (const float*)d_in[15];
  float* out = (float*)d_out;

  char* ws = (char*)d_ws;
  size_t off = 0;
  auto carve = [&](size_t bytes) {
    char* p = ws + off;
    off = (off + bytes + 255) & ~(size_t)255;
    return p;
  };
  float* agg   = (float*)carve((size_t)KN * 64 * 4);   // 25.6 MB
  u16*   h     = (u16*)carve((size_t)KN * 64 * 2);     // 12.8 MB
  u16*   x12   = (u16*)carve((size_t)KN * 64 * 2);     // 12.8 MB (x1 and x2 alias)
  float* a_s   = (float*)carve((size_t)KN * 4);
  float* a_d   = (float*)carve((size_t)KN * 4);
  float* denom = (float*)carve((size_t)KN * 4);
  float* e_arr = (float*)carve((size_t)KEG * 4);
  u16*   wm1t  = (u16*)carve((size_t)33 * 4 * 64 * 8 * 2);
  // total ~55 MB

  const int* gsrc = geidx;
  const int* gdst = geidx + KEG;

  k_wm1t<<<264, 256, 0, stream>>>(Wm1, wm1t);

  // ---- GAT layer 0 ----
  k_init<<<(KN * 64) / 256, 256, 0, stream>>>(agg, denom);
  k_transform0<<<KN / 4, 256, 0, stream>>>(pos, W0, as0, ad0, h, a_s, a_d);
  k_edge_denom<<<(KEG + 255) / 256, 256, 0, stream>>>(gsrc, gdst, a_s, a_d, e_arr, denom);
  k_scatter<<<KEG / 4, 256, 0, stream>>>(gsrc, gdst, h, e_arr, denom, agg);
  k_finalize<<<(KN * 64) / 256, 256, 0, stream>>>(agg, b0, x12);

  // ---- GAT layer 1 ----
  k_init<<<(KN * 64) / 256, 256, 0, stream>>>(agg, denom);
  k_transform1<<<KN / 4, 256, 0, stream>>>(x12, W1, as1, ad1, h, a_s, a_d);
  k_edge_denom<<<(KEG + 255) / 256, 256, 0, stream>>>(gsrc, gdst, a_s, a_d, e_arr, denom);
  k_scatter<<<KEG / 4, 256, 0, stream>>>(gsrc, gdst, h, e_arr, denom, agg);
  k_finalize<<<(KN * 64) / 256, 256, 0, stream>>>(agg, b1, x12);

  // ---- fused edge MLP (MFMA, f32 out) ----
  k_edge_mlp<<<(KE + 255) / 256, 256, 0, stream>>>(eidx, x12, eattr, wm1t, Wm1, bm1, Wm2, bm2, out);
}

// Round 4
// 591.486 us; speedup vs baseline: 1.2116x; 1.2116x over previous
//
#include <hip/hip_runtime.h>

#define KN 100000
#define KEG 600000
#define KE 600000
#define NB 98  // ceil(KN/1024) scan blocks

using u16 = unsigned short;
typedef __bf16 bf16x8 __attribute__((ext_vector_type(8)));
typedef float f32x4 __attribute__((ext_vector_type(4)));

__device__ __forceinline__ float b2f(u16 u) { return __uint_as_float(((unsigned)u) << 16); }
__device__ __forceinline__ u16 f2b(float f) {
  unsigned u = __float_as_uint(f);
  u += 0x7FFF + ((u >> 16) & 1);  // round-to-nearest-even
  return (u16)(u >> 16);
}
__device__ __forceinline__ int imin(int a, int b) { return a < b ? a : b; }

// ---------------- CSR build (once, reused by both GAT layers) ----------------

__global__ __launch_bounds__(256) void k_zero(int* counts, int* cursor) {
  int i = blockIdx.x * 256 + threadIdx.x;
  if (i < KN) { counts[i] = 0; cursor[i] = 0; }
}

__global__ __launch_bounds__(256) void k_hist(const int* __restrict__ gdst, int* __restrict__ counts) {
  int e = blockIdx.x * 256 + threadIdx.x;
  if (e < KEG) atomicAdd(counts + gdst[e], 1);
}

// inclusive scan of 1024-chunks; block totals to bsum
__global__ __launch_bounds__(1024) void k_scan_block(
    const int* __restrict__ counts, int* __restrict__ incl, int* __restrict__ bsum) {
  int gid = blockIdx.x * 1024 + threadIdx.x;
  int lane = threadIdx.x & 63, w = threadIdx.x >> 6;
  int x = (gid < KN) ? counts[gid] : 0;
  for (int off = 1; off < 64; off <<= 1) {
    int y = __shfl_up(x, off);
    if (lane >= off) x += y;
  }
  __shared__ int wtot[16];
  if (lane == 63) wtot[w] = x;
  __syncthreads();
  if (w == 0 && lane < 16) {
    int t = wtot[lane];
    for (int off = 1; off < 16; off <<= 1) {
      int y = __shfl_up(t, off);
      if (lane >= off) t += y;
    }
    wtot[lane] = t;
  }
  __syncthreads();
  if (w > 0) x += wtot[w - 1];
  if (gid < KN) incl[gid] = x;
  if (threadIdx.x == 1023) bsum[blockIdx.x] = x;
}

__global__ __launch_bounds__(128) void k_scan_bsum(int* __restrict__ bsum, int* __restrict__ boff) {
  if (threadIdx.x == 0) {
    int acc = 0;
    for (int i = 0; i < NB; ++i) { int c = bsum[i]; boff[i] = acc; acc += c; }
  }
}

__global__ __launch_bounds__(1024) void k_scan_final(
    const int* __restrict__ incl, const int* __restrict__ counts,
    const int* __restrict__ boff, int* __restrict__ row_start) {
  int gid = blockIdx.x * 1024 + threadIdx.x;
  if (gid < KN) row_start[gid] = incl[gid] - counts[gid] + boff[blockIdx.x];
}

__global__ __launch_bounds__(256) void k_fill(
    const int* __restrict__ gsrc, const int* __restrict__ gdst,
    const int* __restrict__ row_start, int* __restrict__ cursor, int* __restrict__ csr_src) {
  int e = blockIdx.x * 256 + threadIdx.x;
  if (e >= KEG) return;
  int d = gdst[e];
  int pos = atomicAdd(cursor + d, 1);
  csr_src[row_start[d] + pos] = gsrc[e];
}

// ---------------- GAT layers ----------------

// layer0 transform: h = pos @ W0 (in=3), a_s = <h,att_src>, a_d = <h,att_dst>
__global__ __launch_bounds__(256) void k_transform0(
    const float* __restrict__ pos, const float* __restrict__ W0,
    const float* __restrict__ att_s, const float* __restrict__ att_d,
    u16* __restrict__ h, float* __restrict__ a_s, float* __restrict__ a_d) {
  int lane = threadIdx.x & 63;
  int n = blockIdx.x * 4 + (threadIdx.x >> 6);
  if (n >= KN) return;
  float p0 = pos[n * 3 + 0], p1 = pos[n * 3 + 1], p2 = pos[n * 3 + 2];
  float hv = p0 * W0[lane] + p1 * W0[64 + lane] + p2 * W0[128 + lane];
  h[n * 64 + lane] = f2b(hv);
  float s = hv * att_s[lane];
  float d = hv * att_d[lane];
  for (int off = 1; off < 64; off <<= 1) { s += __shfl_xor(s, off); d += __shfl_xor(d, off); }
  if (lane == 0) { a_s[n] = s; a_d[n] = d; }
}

// layer1 transform: h = x1 @ W1 (64x64 via wave shuffle broadcast)
__global__ __launch_bounds__(256) void k_transform1(
    const u16* __restrict__ x, const float* __restrict__ W1,
    const float* __restrict__ att_s, const float* __restrict__ att_d,
    u16* __restrict__ h, float* __restrict__ a_s, float* __restrict__ a_d) {
  int lane = threadIdx.x & 63;
  int n = blockIdx.x * 4 + (threadIdx.x >> 6);
  if (n >= KN) return;
  float xv = b2f(x[n * 64 + lane]);
  float hv = 0.f;
#pragma unroll 16
  for (int k = 0; k < 64; ++k) hv += __shfl(xv, k) * W1[k * 64 + lane];
  h[n * 64 + lane] = f2b(hv);
  float s = hv * att_s[lane];
  float d = hv * att_d[lane];
  for (int off = 1; off < 64; off <<= 1) { s += __shfl_xor(s, off); d += __shfl_xor(d, off); }
  if (lane == 0) { a_s[n] = s; a_d[n] = d; }
}

// fused scatter-softmax + aggregate + bias + ELU: one wave per dst node, no atomics.
// (max-subtraction skipped: alphas O(1..10); weights ex/den identical to shifted form)
__global__ __launch_bounds__(256) void k_gat_agg(
    const int* __restrict__ row_start, const int* __restrict__ counts,
    const int* __restrict__ csr_src, const float* __restrict__ a_s,
    const float* __restrict__ a_d, const u16* __restrict__ h,
    const float* __restrict__ bias, u16* __restrict__ xout) {
  int lane = threadIdx.x & 63;
  int n = blockIdx.x * 4 + (threadIdx.x >> 6);  // always < KN (grid=25000)
  int start = row_start[n], deg = counts[n];
  float adn = a_d[n];
  float acc = 0.f, den = 0.f;
  for (int j = 0; j < deg; ++j) {
    int src = csr_src[start + j];
    float al = a_s[src] + adn;
    al = al > 0.f ? al : 0.2f * al;
    float ex = __expf(al);
    den += ex;
    acc += ex * b2f(h[src * 64 + lane]);
  }
  float v = acc / (den + 1e-16f) + bias[lane];
  v = v > 0.f ? v : expm1f(v);
  xout[n * 64 + lane] = f2b(v);
}

// ---------------- edge MLP ----------------

// Pre-swizzle Wm1 rows 0..127 into MFMA B-fragment order (bf16) and pack the
// per-column epilogue scalars {bm1, wm2, wm1[128], wm1[129]} into float4.
__global__ __launch_bounds__(256) void k_prep(
    const float* __restrict__ wm1, const float* __restrict__ bm1,
    const float* __restrict__ wm2, u16* __restrict__ wm1t, float4* __restrict__ scal) {
  int idx = blockIdx.x * 256 + threadIdx.x;
  if (idx < 33 * 4 * 64 * 8) {
    int j = idx & 7;
    int lane = (idx >> 3) & 63;
    int kt = (idx >> 9) & 3;
    int nt = idx >> 11;
    int n = nt * 16 + (lane & 15);
    int k = kt * 32 + (lane >> 4) * 8 + j;
    wm1t[idx] = (n < 520) ? f2b(wm1[k * 520 + n]) : (u16)0;
  }
  if (idx < 33 * 64) {
    int lane = idx & 63, nt = idx >> 6;
    int col = nt * 16 + (lane & 15);
    float4 v;
    if (col < 520) {
      v.x = bm1[col]; v.y = wm2[col]; v.z = wm1[128 * 520 + col]; v.w = wm1[129 * 520 + col];
    } else {
      v.x = 0.f; v.y = 0.f; v.z = 0.f; v.w = 0.f;
    }
    scal[idx] = v;
  }
}

// Fused edge MLP: gather ef=[x[src],x[dst],ea], GEMM vs Wm1 (K=128 MFMA + rank-2
// VALU for rows 128/129), +bm1, ELU, dot Wm2, +bm2. Wave = 64 edges. B-fragment
// and scalar loads register-double-buffered (prefetch nt+1 during nt compute).
__global__ __launch_bounds__(256) void k_edge_mlp(
    const int* __restrict__ eidx, const u16* __restrict__ x2bf,
    const float* __restrict__ eattr, const u16* __restrict__ wm1t,
    const float4* __restrict__ scal, const float* __restrict__ bm2,
    float* __restrict__ out) {
  int lane = threadIdx.x & 63;
  int wave = threadIdx.x >> 6;
  int base = blockIdx.x * 256 + wave * 64;
  int m = lane & 15, q = lane >> 4;

  // A fragments: A[m=lane&15][k=q*8+j]; whole 16x160 ef tile lives in regs
  bf16x8 A[4][4];
#pragma unroll
  for (int s = 0; s < 4; ++s) {
    int row = imin(base + s * 16 + m, KE - 1);
    int es = eidx[row], ed = eidx[KE + row];
    const bf16x8* ps = (const bf16x8*)(x2bf + es * 64);
    const bf16x8* pd = (const bf16x8*)(x2bf + ed * 64);
    A[s][0] = ps[q];      // k 0..31   (x_src lo)
    A[s][1] = ps[q + 4];  // k 32..63  (x_src hi)
    A[s][2] = pd[q];      // k 64..95  (x_dst lo)
    A[s][3] = pd[q + 4];  // k 96..127 (x_dst hi)
  }

  // edge_attr per C-row (row = q*4+r within subtile)
  float ea0[4][4], ea1[4][4];
#pragma unroll
  for (int s = 0; s < 4; ++s)
#pragma unroll
    for (int r = 0; r < 4; ++r) {
      int row = imin(base + s * 16 + q * 4 + r, KE - 1);
      ea0[s][r] = eattr[row * 2 + 0];
      ea1[s][r] = eattr[row * 2 + 1];
    }

  float osum[4][4];
#pragma unroll
  for (int s = 0; s < 4; ++s)
#pragma unroll
    for (int r = 0; r < 4; ++r) osum[s][r] = 0.f;

  const bf16x8* bt = (const bf16x8*)wm1t;
  bf16x8 B0 = bt[0 * 64 + lane];
  bf16x8 B1 = bt[1 * 64 + lane];
  bf16x8 B2 = bt[2 * 64 + lane];
  bf16x8 B3 = bt[3 * 64 + lane];
  float4 S = scal[lane];

#pragma unroll 1
  for (int nt = 0; nt < 33; ++nt) {
    bf16x8 C0, C1, C2, C3;
    float4 Sn;
    if (nt < 32) {  // prefetch next tile's B fragments + scalars
      C0 = bt[((nt + 1) * 4 + 0) * 64 + lane];
      C1 = bt[((nt + 1) * 4 + 1) * 64 + lane];
      C2 = bt[((nt + 1) * 4 + 2) * 64 + lane];
      C3 = bt[((nt + 1) * 4 + 3) * 64 + lane];
      Sn = scal[(nt + 1) * 64 + lane];
    }
    float bias = S.x, w2 = S.y, w128 = S.z, w129 = S.w;
#pragma unroll
    for (int s = 0; s < 4; ++s) {
      f32x4 acc = {0.f, 0.f, 0.f, 0.f};
      acc = __builtin_amdgcn_mfma_f32_16x16x32_bf16(A[s][0], B0, acc, 0, 0, 0);
      acc = __builtin_amdgcn_mfma_f32_16x16x32_bf16(A[s][1], B1, acc, 0, 0, 0);
      acc = __builtin_amdgcn_mfma_f32_16x16x32_bf16(A[s][2], B2, acc, 0, 0, 0);
      acc = __builtin_amdgcn_mfma_f32_16x16x32_bf16(A[s][3], B3, acc, 0, 0, 0);
#pragma unroll
      for (int r = 0; r < 4; ++r) {  // C/D: col=lane&15, row=q*4+r
        float hv = acc[r] + bias + ea0[s][r] * w128 + ea1[s][r] * w129;
        hv = hv > 0.f ? hv : (__expf(hv) - 1.f);  // ELU
        osum[s][r] += hv * w2;
      }
    }
    if (nt < 32) { B0 = C0; B1 = C1; B2 = C2; B3 = C3; S = Sn; }
  }

  float b2v = bm2[0];
#pragma unroll
  for (int s = 0; s < 4; ++s)
#pragma unroll
    for (int r = 0; r < 4; ++r) {
      float v = osum[s][r];
      v += __shfl_xor(v, 1);
      v += __shfl_xor(v, 2);
      v += __shfl_xor(v, 4);
      v += __shfl_xor(v, 8);  // sum the 16 column-lanes of this row
      if (m == 0) {
        int row = base + s * 16 + q * 4 + r;
        if (row < KE) out[row] = v + b2v;
      }
    }
}

extern "C" void kernel_launch(void* const* d_in, const int* in_sizes, int n_in,
                              void* d_out, int out_size, void* d_ws, size_t ws_size,
                              hipStream_t stream) {
  const float* pos  = (const float*)d_in[0];
  const int* eidx   = (const int*)d_in[1];
  const int* geidx  = (const int*)d_in[2];
  const float* eattr= (const float*)d_in[3];
  const float* W0   = (const float*)d_in[4];
  const float* as0  = (const float*)d_in[5];
  const float* ad0  = (const float*)d_in[6];
  const float* b0   = (const float*)d_in[7];
  const float* W1   = (const float*)d_in[8];
  const float* as1  = (const float*)d_in[9];
  const float* ad1  = (const float*)d_in[10];
  const float* b1   = (const float*)d_in[11];
  const float* Wm1  = (const float*)d_in[12];
  const float* bm1  = (const float*)d_in[13];
  const float* Wm2  = (const float*)d_in[14];
  const float* bm2  = (const float*)d_in[15];
  float* out = (float*)d_out;

  char* ws = (char*)d_ws;
  size_t off = 0;
  auto carve = [&](size_t bytes) {
    char* p = ws + off;
    off = (off + bytes + 255) & ~(size_t)255;
    return p;
  };
  int* counts    = (int*)carve((size_t)KN * 4);
  int* cursor    = (int*)carve((size_t)KN * 4);
  int* incl      = (int*)carve((size_t)KN * 4);
  int* row_start = (int*)carve((size_t)KN * 4);
  int* bsum      = (int*)carve(128 * 4);
  int* boff      = (int*)carve(128 * 4);
  int* csr_src   = (int*)carve((size_t)KEG * 4);
  u16* h         = (u16*)carve((size_t)KN * 64 * 2);
  u16* x12       = (u16*)carve((size_t)KN * 64 * 2);
  float* a_s     = (float*)carve((size_t)KN * 4);
  float* a_d     = (float*)carve((size_t)KN * 4);
  u16* wm1t      = (u16*)carve((size_t)33 * 4 * 64 * 8 * 2);
  float4* scal   = (float4*)carve((size_t)33 * 64 * 16);
  // total ~31 MB

  const int* gsrc = geidx;
  const int* gdst = geidx + KEG;

  // prep + CSR build (graph shared by both layers)
  k_prep<<<264, 256, 0, stream>>>(Wm1, bm1, Wm2, wm1t, scal);
  k_zero<<<(KN + 255) / 256, 256, 0, stream>>>(counts, cursor);
  k_hist<<<(KEG + 255) / 256, 256, 0, stream>>>(gdst, counts);
  k_scan_block<<<NB, 1024, 0, stream>>>(counts, incl, bsum);
  k_scan_bsum<<<1, 128, 0, stream>>>(bsum, boff);
  k_scan_final<<<NB, 1024, 0, stream>>>(incl, counts, boff, row_start);
  k_fill<<<(KEG + 255) / 256, 256, 0, stream>>>(gsrc, gdst, row_start, cursor, csr_src);

  // ---- GAT layer 0 ----
  k_transform0<<<KN / 4, 256, 0, stream>>>(pos, W0, as0, ad0, h, a_s, a_d);
  k_gat_agg<<<KN / 4, 256, 0, stream>>>(row_start, counts, csr_src, a_s, a_d, h, b0, x12);

  // ---- GAT layer 1 ----
  k_transform1<<<KN / 4, 256, 0, stream>>>(x12, W1, as1, ad1, h, a_s, a_d);
  k_gat_agg<<<KN / 4, 256, 0, stream>>>(row_start, counts, csr_src, a_s, a_d, h, b1, x12);

  // ---- fused edge MLP (MFMA, f32 out) ----
  k_edge_mlp<<<(KE + 255) / 256, 256, 0, stream>>>(eidx, x12, eattr, wm1t, scal, bm2, out);
}

// Round 5
// 468.816 us; speedup vs baseline: 1.5287x; 1.2617x over previous
//
#include <hip/hip_runtime.h>

#define KN 100000
#define KEG 600000
#define KE 600000
#define NB 98  // ceil(KN/1024) scan blocks

using u16 = unsigned short;
typedef __bf16 bf16x8 __attribute__((ext_vector_type(8)));
typedef float f32x4 __attribute__((ext_vector_type(4)));

__device__ __forceinline__ float b2f(u16 u) { return __uint_as_float(((unsigned)u) << 16); }
__device__ __forceinline__ u16 f2b(float f) {
  unsigned u = __float_as_uint(f);
  u += 0x7FFF + ((u >> 16) & 1);  // round-to-nearest-even
  return (u16)(u >> 16);
}
__device__ __forceinline__ int imin(int a, int b) { return a < b ? a : b; }

// ---------------- prep: W-swizzles + zero counts (fused) ----------------
// wm1t: 33 nt x 5 frags x 64 lanes x 8 elem. Frags 0..3 = Wm1 rows 0..127 in
// MFMA B layout; frag 4 = K-extension rows [w128, w129, bm1, 0...] so the MFMA
// computes the full pre-activation including edge_attr rank-2 term and bias.
__global__ __launch_bounds__(256) void k_prep(
    const float* __restrict__ wm1, const float* __restrict__ bm1,
    const float* __restrict__ wm2, const float* __restrict__ w1,
    u16* __restrict__ wm1t, u16* __restrict__ w1t, float* __restrict__ wsc,
    int* counts, int* cursor) {
  int idx = blockIdx.x * 256 + threadIdx.x;
  if (idx < KN) { counts[idx] = 0; cursor[idx] = 0; }
  if (idx < 33 * 5 * 64 * 8) {
    int j = idx & 7;
    int lane = (idx >> 3) & 63;
    int f = (idx >> 9) % 5;
    int nt = idx / (512 * 5);
    int n = nt * 16 + (lane & 15);
    float v = 0.f;
    if (n < 520) {
      if (f < 4) {
        int k = f * 32 + (lane >> 4) * 8 + j;
        v = wm1[k * 520 + n];
      } else {
        int kk = (lane >> 4) * 8 + j;  // 0..31 -> rows 128..159
        if (kk == 0) v = wm1[128 * 520 + n];
        else if (kk == 1) v = wm1[129 * 520 + n];
        else if (kk == 2) v = bm1[n];
      }
    }
    wm1t[idx] = f2b(v);
  }
  if (idx < 33 * 64) {
    int lane = idx & 63, nt = idx >> 6;
    int col = nt * 16 + (lane & 15);
    wsc[idx] = (col < 520) ? wm2[col] : 0.f;
  }
  if (idx < 4 * 2 * 64 * 8) {  // W1 [64k x 64n] -> MFMA B frags (4 nt x 2 kt)
    int j = idx & 7;
    int lane = (idx >> 3) & 63;
    int kt = (idx >> 9) & 1;
    int nt = idx >> 10;
    int n = nt * 16 + (lane & 15);
    int k = kt * 32 + (lane >> 4) * 8 + j;
    w1t[idx] = f2b(w1[k * 64 + n]);
  }
}

// ---------------- CSR build ----------------

__global__ __launch_bounds__(256) void k_hist(const int* __restrict__ gdst, int* __restrict__ counts) {
  int e = blockIdx.x * 256 + threadIdx.x;
  if (e < KEG) atomicAdd(counts + gdst[e], 1);
}

__global__ __launch_bounds__(1024) void k_scan_block(
    const int* __restrict__ counts, int* __restrict__ incl, int* __restrict__ bsum) {
  int gid = blockIdx.x * 1024 + threadIdx.x;
  int lane = threadIdx.x & 63, w = threadIdx.x >> 6;
  int x = (gid < KN) ? counts[gid] : 0;
  for (int off = 1; off < 64; off <<= 1) {
    int y = __shfl_up(x, off);
    if (lane >= off) x += y;
  }
  __shared__ int wtot[16];
  if (lane == 63) wtot[w] = x;
  __syncthreads();
  if (w == 0 && lane < 16) {
    int t = wtot[lane];
    for (int off = 1; off < 16; off <<= 1) {
      int y = __shfl_up(t, off);
      if (lane >= off) t += y;
    }
    wtot[lane] = t;
  }
  __syncthreads();
  if (w > 0) x += wtot[w - 1];
  if (gid < KN) incl[gid] = x;
  if (threadIdx.x == 1023) bsum[blockIdx.x] = x;
}

// one-wave shuffle scan over NB<=128 block sums (was serial 98-iter loop)
__global__ __launch_bounds__(64) void k_scan_bsum(const int* __restrict__ bsum, int* __restrict__ boff) {
  int lane = threadIdx.x;
  int x0 = (lane < NB) ? bsum[lane] : 0;
  int x1 = (64 + lane < NB) ? bsum[64 + lane] : 0;
  int i0 = x0, i1 = x1;
  for (int off = 1; off < 64; off <<= 1) {
    int y0 = __shfl_up(i0, off), y1 = __shfl_up(i1, off);
    if (lane >= off) { i0 += y0; i1 += y1; }
  }
  int tot0 = __shfl(i0, 63);
  if (lane < NB) boff[lane] = i0 - x0;
  if (64 + lane < NB) boff[64 + lane] = i1 - x1 + tot0;
}

__global__ __launch_bounds__(1024) void k_scan_final(
    const int* __restrict__ incl, const int* __restrict__ counts,
    const int* __restrict__ boff, int* __restrict__ row_start) {
  int gid = blockIdx.x * 1024 + threadIdx.x;
  if (gid < KN) row_start[gid] = incl[gid] - counts[gid] + boff[blockIdx.x];
}

__global__ __launch_bounds__(256) void k_fill(
    const int* __restrict__ gsrc, const int* __restrict__ gdst,
    const int* __restrict__ row_start, int* __restrict__ cursor, int* __restrict__ csr_src) {
  int e = blockIdx.x * 256 + threadIdx.x;
  if (e >= KEG) return;
  int d = gdst[e];
  int pos = atomicAdd(cursor + d, 1);
  csr_src[row_start[d] + pos] = gsrc[e];
}

// ---------------- GAT layers ----------------

__global__ __launch_bounds__(256) void k_transform0(
    const float* __restrict__ pos, const float* __restrict__ W0,
    const float* __restrict__ att_s, const float* __restrict__ att_d,
    u16* __restrict__ h, float* __restrict__ a_s, float* __restrict__ a_d) {
  int lane = threadIdx.x & 63;
  int n = blockIdx.x * 4 + (threadIdx.x >> 6);
  if (n >= KN) return;
  float p0 = pos[n * 3 + 0], p1 = pos[n * 3 + 1], p2 = pos[n * 3 + 2];
  float hv = p0 * W0[lane] + p1 * W0[64 + lane] + p2 * W0[128 + lane];
  h[n * 64 + lane] = f2b(hv);
  float s = hv * att_s[lane];
  float d = hv * att_d[lane];
  for (int off = 1; off < 64; off <<= 1) { s += __shfl_xor(s, off); d += __shfl_xor(d, off); }
  if (lane == 0) { a_s[n] = s; a_d[n] = d; }
}

// layer1 transform via MFMA: 16 nodes/wave, h = x @ W1 (64x64), fused a_s/a_d.
__global__ __launch_bounds__(256) void k_transform1(
    const u16* __restrict__ x, const u16* __restrict__ w1t,
    const float* __restrict__ att_s, const float* __restrict__ att_d,
    u16* __restrict__ h, float* __restrict__ a_s, float* __restrict__ a_d) {
  int lane = threadIdx.x & 63;
  int wave = threadIdx.x >> 6;
  int nodebase = blockIdx.x * 64 + wave * 16;
  int m = lane & 15, q = lane >> 4;

  int node = imin(nodebase + m, KN - 1);
  const bf16x8* px = (const bf16x8*)(x + node * 64);
  bf16x8 A0 = px[q];      // k 0..31
  bf16x8 A1 = px[q + 4];  // k 32..63

  const bf16x8* bt = (const bf16x8*)w1t;
  float ps[4] = {0.f, 0.f, 0.f, 0.f};
  float pd[4] = {0.f, 0.f, 0.f, 0.f};
#pragma unroll
  for (int nt = 0; nt < 4; ++nt) {
    int col = nt * 16 + m;
    float asv = att_s[col], adv = att_d[col];
    f32x4 acc = {0.f, 0.f, 0.f, 0.f};
    acc = __builtin_amdgcn_mfma_f32_16x16x32_bf16(A0, bt[(nt * 2 + 0) * 64 + lane], acc, 0, 0, 0);
    acc = __builtin_amdgcn_mfma_f32_16x16x32_bf16(A1, bt[(nt * 2 + 1) * 64 + lane], acc, 0, 0, 0);
#pragma unroll
    for (int r = 0; r < 4; ++r) {  // C/D: col=lane&15 -> output col, row=q*4+r -> node
      int rown = nodebase + q * 4 + r;
      if (rown < KN) h[rown * 64 + col] = f2b(acc[r]);
      ps[r] += acc[r] * asv;
      pd[r] += acc[r] * adv;
    }
  }
#pragma unroll
  for (int r = 0; r < 4; ++r) {
    float s = ps[r], d = pd[r];
    s += __shfl_xor(s, 1); d += __shfl_xor(d, 1);
    s += __shfl_xor(s, 2); d += __shfl_xor(d, 2);
    s += __shfl_xor(s, 4); d += __shfl_xor(d, 4);
    s += __shfl_xor(s, 8); d += __shfl_xor(d, 8);
    int rown = nodebase + q * 4 + r;
    if (m == 0 && rown < KN) { a_s[rown] = s; a_d[rown] = d; }
  }
}

// fused scatter-softmax + aggregate + bias + ELU: one wave per dst node, no atomics,
// src-index software-pipelined. (max-subtraction skipped: alphas O(1..10))
__global__ __launch_bounds__(256) void k_gat_agg(
    const int* __restrict__ row_start, const int* __restrict__ counts,
    const int* __restrict__ csr_src, const float* __restrict__ a_s,
    const float* __restrict__ a_d, const u16* __restrict__ h,
    const float* __restrict__ bias, u16* __restrict__ xout) {
  int lane = threadIdx.x & 63;
  int n = blockIdx.x * 4 + (threadIdx.x >> 6);  // grid covers KN exactly (25000 blocks)
  int start = row_start[n], deg = counts[n];
  float adn = a_d[n];
  float acc = 0.f, den = 0.f;
  int s0 = (deg > 0) ? csr_src[start] : 0;
  for (int j = 0; j < deg; ++j) {
    int s1 = (j + 1 < deg) ? csr_src[start + j + 1] : s0;  // prefetch next index
    float as = a_s[s0];
    float hv = b2f(h[s0 * 64 + lane]);
    float al = as + adn;
    al = al > 0.f ? al : 0.2f * al;
    float ex = __expf(al);
    den += ex;
    acc += ex * hv;
    s0 = s1;
  }
  float v = acc / (den + 1e-16f) + bias[lane];
  v = v > 0.f ? v : expm1f(v);
  xout[n * 64 + lane] = f2b(v);
}

// ---------------- edge MLP ----------------
// K=160 MFMA (features 128 + [ea0,ea1,1.0] fold -> pre-activation directly).
// Epilogue per element: v = max(acc,0)+exp(min(acc,0)) = elu(acc)+1;
// osum += v*w2, corrected by -sum(w2) once at the end.
__global__ __launch_bounds__(256) void k_edge_mlp(
    const int* __restrict__ eidx, const u16* __restrict__ x2bf,
    const float* __restrict__ eattr, const u16* __restrict__ wm1t,
    const float* __restrict__ wsc, const float* __restrict__ bm2,
    float* __restrict__ out) {
  int lane = threadIdx.x & 63;
  int wave = threadIdx.x >> 6;
  int base = blockIdx.x * 256 + wave * 64;
  int m = lane & 15, q = lane >> 4;

  // A fragments: A[m=lane&15][k=q*8+j]
  bf16x8 A[4][5];
#pragma unroll
  for (int s = 0; s < 4; ++s) {
    int row = imin(base + s * 16 + m, KE - 1);
    int es = eidx[row], ed = eidx[KE + row];
    const bf16x8* psrc = (const bf16x8*)(x2bf + es * 64);
    const bf16x8* pdst = (const bf16x8*)(x2bf + ed * 64);
    A[s][0] = psrc[q];      // k 0..31   (x_src lo)
    A[s][1] = psrc[q + 4];  // k 32..63  (x_src hi)
    A[s][2] = pdst[q];      // k 64..95  (x_dst lo)
    A[s][3] = pdst[q + 4];  // k 96..127 (x_dst hi)
    bf16x8 a5 = {0, 0, 0, 0, 0, 0, 0, 0};
    if (q == 0) {  // k 128..135: [ea0, ea1, 1, 0...]
      a5[0] = (__bf16)eattr[row * 2 + 0];
      a5[1] = (__bf16)eattr[row * 2 + 1];
      a5[2] = (__bf16)1.0f;
    }
    A[s][4] = a5;
  }

  float osum[4][4];
#pragma unroll
  for (int s = 0; s < 4; ++s)
#pragma unroll
    for (int r = 0; r < 4; ++r) osum[s][r] = 0.f;

  const bf16x8* bt = (const bf16x8*)wm1t;
  float w2tot = 0.f;
#pragma unroll 1
  for (int nt = 0; nt < 33; ++nt) {
    bf16x8 B0 = bt[(nt * 5 + 0) * 64 + lane];
    bf16x8 B1 = bt[(nt * 5 + 1) * 64 + lane];
    bf16x8 B2 = bt[(nt * 5 + 2) * 64 + lane];
    bf16x8 B3 = bt[(nt * 5 + 3) * 64 + lane];
    bf16x8 B4 = bt[(nt * 5 + 4) * 64 + lane];
    float w2 = wsc[nt * 64 + lane];
    w2tot += w2;
#pragma unroll
    for (int s = 0; s < 4; ++s) {
      f32x4 acc = {0.f, 0.f, 0.f, 0.f};
      acc = __builtin_amdgcn_mfma_f32_16x16x32_bf16(A[s][0], B0, acc, 0, 0, 0);
      acc = __builtin_amdgcn_mfma_f32_16x16x32_bf16(A[s][1], B1, acc, 0, 0, 0);
      acc = __builtin_amdgcn_mfma_f32_16x16x32_bf16(A[s][2], B2, acc, 0, 0, 0);
      acc = __builtin_amdgcn_mfma_f32_16x16x32_bf16(A[s][3], B3, acc, 0, 0, 0);
      acc = __builtin_amdgcn_mfma_f32_16x16x32_bf16(A[s][4], B4, acc, 0, 0, 0);
#pragma unroll
      for (int r = 0; r < 4; ++r) {  // acc[r] = full pre-activation
        float t = fminf(acc[r], 0.f);
        float p = fmaxf(acc[r], 0.f);
        float v = p + __expf(t);  // = elu(acc)+1
        osum[s][r] += v * w2;
      }
    }
  }

  float b2v = bm2[0];
#pragma unroll
  for (int s = 0; s < 4; ++s)
#pragma unroll
    for (int r = 0; r < 4; ++r) {
      float v = osum[s][r] - w2tot;  // undo the +1 in elu+1
      v += __shfl_xor(v, 1);
      v += __shfl_xor(v, 2);
      v += __shfl_xor(v, 4);
      v += __shfl_xor(v, 8);  // sum over the 16 column-lanes
      if (m == 0) {
        int row = base + s * 16 + q * 4 + r;
        if (row < KE) out[row] = v + b2v;
      }
    }
}

extern "C" void kernel_launch(void* const* d_in, const int* in_sizes, int n_in,
                              void* d_out, int out_size, void* d_ws, size_t ws_size,
                              hipStream_t stream) {
  const float* pos  = (const float*)d_in[0];
  const int* eidx   = (const int*)d_in[1];
  const int* geidx  = (const int*)d_in[2];
  const float* eattr= (const float*)d_in[3];
  const float* W0   = (const float*)d_in[4];
  const float* as0  = (const float*)d_in[5];
  const float* ad0  = (const float*)d_in[6];
  const float* b0   = (const float*)d_in[7];
  const float* W1   = (const float*)d_in[8];
  const float* as1  = (const float*)d_in[9];
  const float* ad1  = (const float*)d_in[10];
  const float* b1   = (const float*)d_in[11];
  const float* Wm1  = (const float*)d_in[12];
  const float* bm1  = (const float*)d_in[13];
  const float* Wm2  = (const float*)d_in[14];
  const float* bm2  = (const float*)d_in[15];
  float* out = (float*)d_out;

  char* ws = (char*)d_ws;
  size_t off = 0;
  auto carve = [&](size_t bytes) {
    char* p = ws + off;
    off = (off + bytes + 255) & ~(size_t)255;
    return p;
  };
  int* counts    = (int*)carve((size_t)KN * 4);
  int* cursor    = (int*)carve((size_t)KN * 4);
  int* incl      = (int*)carve((size_t)KN * 4);
  int* row_start = (int*)carve((size_t)KN * 4);
  int* bsum      = (int*)carve(128 * 4);
  int* boff      = (int*)carve(128 * 4);
  int* csr_src   = (int*)carve((size_t)KEG * 4);
  u16* h         = (u16*)carve((size_t)KN * 64 * 2);
  u16* x12       = (u16*)carve((size_t)KN * 64 * 2);
  float* a_s     = (float*)carve((size_t)KN * 4);
  float* a_d     = (float*)carve((size_t)KN * 4);
  u16* wm1t      = (u16*)carve((size_t)33 * 5 * 64 * 8 * 2);
  u16* w1t       = (u16*)carve((size_t)4 * 2 * 64 * 8 * 2);
  float* wsc     = (float*)carve((size_t)33 * 64 * 4);
  // total ~31 MB

  const int* gsrc = geidx;
  const int* gdst = geidx + KEG;

  // prep (W swizzles + zeroing) + CSR build (graph shared by both layers)
  k_prep<<<(KN + 255) / 256, 256, 0, stream>>>(Wm1, bm1, Wm2, W1, wm1t, w1t, wsc, counts, cursor);
  k_hist<<<(KEG + 255) / 256, 256, 0, stream>>>(gdst, counts);
  k_scan_block<<<NB, 1024, 0, stream>>>(counts, incl, bsum);
  k_scan_bsum<<<1, 64, 0, stream>>>(bsum, boff);
  k_scan_final<<<NB, 1024, 0, stream>>>(incl, counts, boff, row_start);
  k_fill<<<(KEG + 255) / 256, 256, 0, stream>>>(gsrc, gdst, row_start, cursor, csr_src);

  // ---- GAT layer 0 ----
  k_transform0<<<KN / 4, 256, 0, stream>>>(pos, W0, as0, ad0, h, a_s, a_d);
  k_gat_agg<<<KN / 4, 256, 0, stream>>>(row_start, counts, csr_src, a_s, a_d, h, b0, x12);

  // ---- GAT layer 1 ----
  k_transform1<<<(KN + 63) / 64, 256, 0, stream>>>(x12, w1t, as1, ad1, h, a_s, a_d);
  k_gat_agg<<<KN / 4, 256, 0, stream>>>(row_start, counts, csr_src, a_s, a_d, h, b1, x12);

  // ---- fused edge MLP (MFMA K=160, f32 out) ----
  k_edge_mlp<<<(KE + 255) / 256, 256, 0, stream>>>(eidx, x12, eattr, wm1t, wsc, bm2, out);
}